// Round 14
// baseline (1698.430 us; speedup 1.0000x reference)
//
#include <hip/hip_runtime.h>
#include <stdint.h>

// LSTM B=64,T=512,I=512,H=512. out hs[T,B,H] fp32.
// R14 = R11 skeleton x TWO INTERLEAVED CHAINS per wg (latency hiding).
// 8 independent chains (8 batch rows each). 128 wgs; wg w serves chains
// (2p, 2p+1), p = w>>5, rank = w&31 -> 16 h-cols. Weights (K=1024) shared
// between chains, held in regs as bf16 MFMA fragments, transposed-C:
// acc = mfma(W_frag, A_frag) -> lane's 4 accs = gates {i,f,g,o} of one
// (batch,col). Per pair-iter: [stepA; stepB]. Each chain-step = R11:
// phase A (x MFMAs), stage x_{t+1}, tagged poll (4x dwordx4 sc0 sc1 +
// vmcnt in one asm; full re-read retry), restage H, ONE barrier, x_{t+2}
// prefetch, phase C (h MFMAs), elementwise (rcp), publish tagged u64.
// By the time chain X's poll runs, X(t) was published ~1 full other-chain
// step earlier -> visibility stall hidden -> first-round hits.
// h words: self-describing u64 [data:32|tag:32], relaxed agent atomics.

#define BATCH 64
#define TSTEPS 512
#define IDIM 512
#define HDIM 512
#define NCH 8                         // independent chains
#define BB 8                          // batch rows per chain
#define NWG 128
#define HDAT_U64 (BB * (HDIM / 2))    // 2048 u64 = 16KB per (parity,chain)

typedef __attribute__((ext_vector_type(4))) float f32x4;
typedef __attribute__((ext_vector_type(8))) short bf16x8;
typedef __attribute__((ext_vector_type(4))) unsigned int u32x4;
typedef __attribute__((ext_vector_type(2))) unsigned int u32x2;

#define AS(p, v) __hip_atomic_store((p), (v), __ATOMIC_RELAXED, __HIP_MEMORY_SCOPE_AGENT)

__device__ inline unsigned short f2bf(float f) {
  unsigned u = __builtin_bit_cast(unsigned, f);
  u = (u + 0x7fffu + ((u >> 16) & 1u)) >> 16;  // RNE
  return (unsigned short)u;
}
__device__ inline float fast_sigmoid(float x) {
  return __builtin_amdgcn_rcpf(1.f + __expf(-x));
}
__device__ inline float fast_tanh(float x) {
  return 1.f - 2.f * __builtin_amdgcn_rcpf(__expf(2.f * x) + 1.f);
}

__global__ void lstm_init(const float* __restrict__ b_ih, const float* __restrict__ b_hh,
                          float* __restrict__ bias, uint64_t* __restrict__ hdat) {
  const int i = blockIdx.x * blockDim.x + threadIdx.x;  // 2048 threads
  if (i < 4 * HDIM) bias[i] = b_ih[i] + b_hh[i];
  // zero tagged words (tag 0 never matches t>=1); clears graph-replay state
  for (int j = i; j < 2 * NCH * HDAT_U64; j += 2048) hdat[j] = 0ull;
}

__global__ __launch_bounds__(256, 1)
void lstm_persistent(const float* __restrict__ x,
                     const float* __restrict__ w_ih,
                     const float* __restrict__ w_hh,
                     const float* __restrict__ bias,
                     uint64_t* hdat,     // [2][NCH][2048] tagged pairs
                     float* __restrict__ out) {
  __shared__ unsigned short XA_lds[2][8 * IDIM];   // 16KB
  __shared__ unsigned short HA_lds[2][8 * HDIM];   // 16KB
  __shared__ unsigned short XB_lds[2][8 * IDIM];   // 16KB
  __shared__ unsigned short HB_lds[2][8 * HDIM];   // 16KB

  const int wg = blockIdx.x;
  const int pair = wg >> 5;            // 0..3
  const int rank = wg & 31;
  const int chA = pair * 2;
  const int chB = pair * 2 + 1;
  const int b0A = chA * BB;
  const int b0B = chB * BB;
  const int h0 = rank * 16;
  const int tid = threadIdx.x;
  const int wave = tid >> 6;
  const int lane = tid & 63;
  const int hi4 = lane >> 4;
  const int nn = lane & 15;

  // ---- one-time: weight A-fragments (transposed-C form), SHARED ----
  const int growf = (nn & 3) * HDIM + h0 + wave * 4 + (nn >> 2);  // gate row
  bf16x8 breg[32];
#pragma unroll
  for (int kt = 0; kt < 32; ++kt) {
    const int k = kt * 32 + hi4 * 8;
    const float* src = (k < IDIM) ? (w_ih + (size_t)growf * IDIM + k)
                                  : (w_hh + (size_t)growf * HDIM + (k - IDIM));
    bf16x8 v;
#pragma unroll
    for (int j = 0; j < 8; ++j) v[j] = (short)f2bf(src[j]);
    breg[kt] = v;
  }
  const int mycol = h0 + wave * 4 + hi4;
  const float bv0 = bias[0 * HDIM + mycol];
  const float bv1 = bias[1 * HDIM + mycol];
  const float bv2 = bias[2 * HDIM + mycol];
  const float bv3 = bias[3 * HDIM + mycol];

  const int bi = lane & 15;          // C col = batch (bi>=8 lanes are dupes)
  const int mr8 = bi & 7;            // MFMA B-row / LDS row (8 real rows)
  const int rswz = mr8 << 4;

  // ---- helpers as macros (static reg names; no runtime array idx) ----
#define STAGE_X(XL, buf, fa, fb, r)                                          \
  {                                                                          \
    bf16x8 v_;                                                               \
    v_[0] = (short)f2bf(fa.x); v_[1] = (short)f2bf(fa.y);                    \
    v_[2] = (short)f2bf(fa.z); v_[3] = (short)f2bf(fa.w);                    \
    v_[4] = (short)f2bf(fb.x); v_[5] = (short)f2bf(fb.y);                    \
    v_[6] = (short)f2bf(fb.z); v_[7] = (short)f2bf(fb.w);                    \
    *(bf16x8*)((char*)&XL[buf][0] + (((r) * 1024 + lane * 16) ^ (((r) & 7) << 4))) = v_; \
  }

  // ---- prologue: stage x_0 for both chains; preload x_1 into P banks ----
#pragma unroll
  for (int q = 0; q < 2; ++q) {
    const int r = wave + q * 4;
    const float* xpA = x + ((size_t)(b0A + r) * TSTEPS + 0) * IDIM + lane * 8;
    float4 fa = *(const float4*)xpA, fb = *(const float4*)(xpA + 4);
    STAGE_X(XA_lds, 0, fa, fb, r)
    const float* xpB = x + ((size_t)(b0B + r) * TSTEPS + 0) * IDIM + lane * 8;
    fa = *(const float4*)xpB; fb = *(const float4*)(xpB + 4);
    STAGE_X(XB_lds, 0, fa, fb, r)
  }
  float4 xfPA[4], xfQA[4], xfPB[4], xfQB[4];
#pragma unroll
  for (int q = 0; q < 2; ++q) {
    const float* xpA = x + ((size_t)(b0A + wave + q * 4) * TSTEPS + 1) * IDIM + lane * 8;
    xfPA[q * 2] = *(const float4*)xpA; xfPA[q * 2 + 1] = *(const float4*)(xpA + 4);
    const float* xpB = x + ((size_t)(b0B + wave + q * 4) * TSTEPS + 1) * IDIM + lane * 8;
    xfPB[q * 2] = *(const float4*)xpB; xfPB[q * 2 + 1] = *(const float4*)(xpB + 4);
  }
  __syncthreads();

  float cA = 0.f, cB = 0.f;
  float houtA[4], houtB[4];
  const size_t obaseA = (size_t)(b0A + bi) * HDIM + mycol;   // valid for bi<8
  const size_t obaseB = (size_t)(b0B + bi) * HDIM + mycol;

  // one full chain-step (R11 skeleton), macro-expanded per chain
#define CHAIN_STEP(XL, HL, cc, xfP, xfQ, chid, b0c, houtc)                   \
  {                                                                          \
    const int cur = t & 1;                                                   \
    /* phase A: x-part MFMAs */                                              \
    f32x4 acc0 = {0.f, 0.f, 0.f, 0.f}, acc1 = {0.f, 0.f, 0.f, 0.f};          \
    _Pragma("unroll")                                                        \
    for (int kt = 0; kt < 16; kt += 2) {                                     \
      bf16x8 a0 = *(const bf16x8*)((const char*)&XL[cur][0] +                \
                    ((mr8 * 1024 + (kt * 4 + hi4) * 16) ^ rswz));            \
      acc0 = __builtin_amdgcn_mfma_f32_16x16x32_bf16(breg[kt], a0, acc0, 0, 0, 0); \
      bf16x8 a1 = *(const bf16x8*)((const char*)&XL[cur][0] +                \
                    ((mr8 * 1024 + ((kt + 1) * 4 + hi4) * 16) ^ rswz));      \
      acc1 = __builtin_amdgcn_mfma_f32_16x16x32_bf16(breg[kt + 1], a1, acc1, 0, 0, 0); \
    }                                                                        \
    /* stage x_{t+1} */                                                      \
    if (t + 1 < TSTEPS) {                                                    \
      _Pragma("unroll")                                                      \
      for (int q = 0; q < 2; ++q) {                                          \
        float4 fa, fb;                                                       \
        if ((u & 1) == 0) { fa = xfP[q * 2]; fb = xfP[q * 2 + 1]; }          \
        else              { fa = xfQ[q * 2]; fb = xfQ[q * 2 + 1]; }          \
        const int r = wave + q * 4;                                          \
        STAGE_X(XL, cur ^ 1, fa, fb, r)                                      \
      }                                                                      \
    }                                                                        \
    /* tagged poll + restage */                                              \
    if (t > 0) {                                                             \
      const uint64_t* dp = hdat + ((size_t)cur * NCH + (chid)) * HDAT_U64    \
                         + (size_t)wave * 512 + lane * 2;                    \
      u32x4 d0, d1, d2, d3;                                                  \
      const uint32_t tu = (uint32_t)t;                                       \
      while (true) {                                                         \
        asm volatile(                                                        \
          "global_load_dwordx4 %0, %4, off sc0 sc1\n\t"                      \
          "global_load_dwordx4 %1, %4, off offset:1024 sc0 sc1\n\t"          \
          "global_load_dwordx4 %2, %4, off offset:2048 sc0 sc1\n\t"          \
          "global_load_dwordx4 %3, %4, off offset:3072 sc0 sc1\n\t"          \
          "s_waitcnt vmcnt(0)"                                               \
          : "=&v"(d0), "=&v"(d1), "=&v"(d2), "=&v"(d3)                       \
          : "v"(dp) : "memory");                                             \
        __builtin_amdgcn_sched_barrier(0);                                   \
        bool ok = (d0[0] == tu) & (d0[2] == tu) & (d1[0] == tu) & (d1[2] == tu) \
                & (d2[0] == tu) & (d2[2] == tu) & (d3[0] == tu) & (d3[2] == tu); \
        if (__all((int)ok)) break;                                           \
      }                                                                      \
      _Pragma("unroll")                                                      \
      for (int j = 0; j < 4; ++j) {                                          \
        const int row = wave * 2 + (j >> 1);                                 \
        const int byte = (row * 1024 + (j & 1) * 512 + lane * 8) ^ ((row & 7) << 4); \
        u32x2 w;                                                             \
        if (j == 0)      { w[0] = d0[1]; w[1] = d0[3]; }                     \
        else if (j == 1) { w[0] = d1[1]; w[1] = d1[3]; }                     \
        else if (j == 2) { w[0] = d2[1]; w[1] = d2[3]; }                     \
        else             { w[0] = d3[1]; w[1] = d3[3]; }                     \
        *(u32x2*)((char*)&HL[cur][0] + byte) = w;                            \
      }                                                                      \
    }                                                                        \
    __syncthreads();   /* one barrier per chain-step */                      \
    /* x_{t+2} refill (post-barrier) */                                      \
    if (t + 2 < TSTEPS) {                                                    \
      _Pragma("unroll")                                                      \
      for (int q = 0; q < 2; ++q) {                                          \
        const float* xp = x + ((size_t)((b0c) + wave + q * 4) * TSTEPS + (t + 2)) * IDIM + lane * 8; \
        if ((u & 1) == 0) { xfQ[q * 2] = *(const float4*)xp; xfQ[q * 2 + 1] = *(const float4*)(xp + 4); } \
        else              { xfP[q * 2] = *(const float4*)xp; xfP[q * 2 + 1] = *(const float4*)(xp + 4); } \
      }                                                                      \
    }                                                                        \
    __builtin_amdgcn_sched_barrier(0);                                       \
    /* phase C: h-part MFMAs */                                              \
    if (t > 0) {                                                             \
      _Pragma("unroll")                                                      \
      for (int kt = 0; kt < 16; kt += 2) {                                   \
        bf16x8 a0 = *(const bf16x8*)((const char*)&HL[cur][0] +              \
                      ((mr8 * 1024 + (kt * 4 + hi4) * 16) ^ rswz));          \
        acc0 = __builtin_amdgcn_mfma_f32_16x16x32_bf16(breg[16 + kt], a0, acc0, 0, 0, 0); \
        bf16x8 a1 = *(const bf16x8*)((const char*)&HL[cur][0] +              \
                      ((mr8 * 1024 + ((kt + 1) * 4 + hi4) * 16) ^ rswz));    \
        acc1 = __builtin_amdgcn_mfma_f32_16x16x32_bf16(breg[17 + kt], a1, acc1, 0, 0, 0); \
      }                                                                      \
    }                                                                        \
    /* elementwise + publish */                                              \
    const float gi = acc0[0] + acc1[0] + bv0;                                \
    const float gf = acc0[1] + acc1[1] + bv1;                                \
    const float gg = acc0[2] + acc1[2] + bv2;                                \
    const float go = acc0[3] + acc1[3] + bv3;                                \
    cc = fast_sigmoid(gf) * cc + fast_sigmoid(gi) * fast_tanh(gg);           \
    const float hval = fast_sigmoid(go) * fast_tanh(cc);                     \
    if (t + 1 < TSTEPS) {                                                    \
      const unsigned hb = (unsigned)f2bf(hval);                              \
      const unsigned pb = (unsigned)__shfl_xor((int)hb, 16, 64);             \
      if (bi < 8 && (hi4 & 1) == 0) {                                        \
        const uint64_t val = (uint64_t)(uint32_t)(t + 1)                     \
                           | ((uint64_t)(hb | (pb << 16)) << 32);            \
        AS(hdat + ((size_t)((t + 1) & 1) * NCH + (chid)) * HDAT_U64          \
             + (size_t)bi * 256 + (mycol >> 1), val);                        \
      }                                                                      \
    }                                                                        \
    houtc[u] = hval;                                                         \
  }

  for (int tb = 0; tb < TSTEPS; tb += 4) {
#pragma unroll
    for (int u = 0; u < 4; ++u) {
      const int t = tb + u;
      CHAIN_STEP(XA_lds, HA_lds, cA, xfPA, xfQA, chA, b0A, houtA)
      CHAIN_STEP(XB_lds, HB_lds, cB, xfPB, xfQB, chB, b0B, houtB)
    }
    // ---- batched out flush (once per 4 steps, both chains) ----
    if (bi < 8) {
#pragma unroll
      for (int k = 0; k < 4; ++k) {
        out[(size_t)(tb + k) * (BATCH * HDIM) + obaseA] = houtA[k];
        out[(size_t)(tb + k) * (BATCH * HDIM) + obaseB] = houtB[k];
      }
    }
  }
#undef CHAIN_STEP
#undef STAGE_X
}

extern "C" void kernel_launch(void* const* d_in, const int* in_sizes, int n_in,
                              void* d_out, int out_size, void* d_ws, size_t ws_size,
                              hipStream_t stream) {
  const float* x    = (const float*)d_in[0];
  const float* w_ih = (const float*)d_in[1];
  const float* w_hh = (const float*)d_in[2];
  const float* b_ih = (const float*)d_in[3];
  const float* b_hh = (const float*)d_in[4];
  float* out = (float*)d_out;

  char* ws = (char*)d_ws;
  float* bias = (float*)ws;                              // 8KB
  uint64_t* hdat = (uint64_t*)(ws + 8192);               // 256KB tagged pairs

  lstm_init<<<8, 256, 0, stream>>>(b_ih, b_hh, bias, hdat);
  lstm_persistent<<<NWG, 256, 0, stream>>>(x, w_ih, w_hh, bias, hdat, out);
}